// Round 4
// baseline (362.177 us; speedup 1.0000x reference)
//
#include <hip/hip_runtime.h>
#include <hip/hip_bf16.h>
#include <stdint.h>

// Problem constants
#define T_TOK 1024
#define DIN   2048
#define NOUT  8192   // 2*O
#define OSL   4096   // O per slice
#define ROWS_PAD 1408
#define BM 128
#define BN 128
#define BK 32

typedef _Float16 f16x8 __attribute__((ext_vector_type(8)));
typedef _Float16 f16x2 __attribute__((ext_vector_type(2)));
typedef float    f32x4 __attribute__((ext_vector_type(4)));

__device__ __forceinline__ void gload16(const void* gp, void* lp) {
  __builtin_amdgcn_global_load_lds(
      (__attribute__((address_space(1))) void*)gp,
      (__attribute__((address_space(3))) void*)lp, 16, 0, 0);
}

__device__ __forceinline__ f16x2 u2h(uint32_t u) {
  union { uint32_t u; f16x2 h; } c; c.u = u; return c.h;
}

__device__ __forceinline__ f16x8 cvt_interleave(float4 f0, float4 f1) {
  // k-order [0,4,1,5,2,6,3,7] so packed-nibble pairs (n_j, n_{j+4}) line up
  f16x8 h;
  h[0] = (_Float16)f0.x; h[1] = (_Float16)f1.x;
  h[2] = (_Float16)f0.y; h[3] = (_Float16)f1.y;
  h[4] = (_Float16)f0.z; h[5] = (_Float16)f1.z;
  h[6] = (_Float16)f0.w; h[7] = (_Float16)f1.w;
  return h;
}

// ================= kernel 1: sort + x->fp16 + Wb->fp16, one launch =================
// blocks: [0] sort | [1, 1+T_TOK] x rows (last = zero pad row) | rest: wbh rows
__global__ void prep_all(const float* __restrict__ x, const float* __restrict__ wb,
                         const int* __restrict__ indices,
                         _Float16* __restrict__ xh,    // [T_TOK+1][DIN], row T_TOK = zeros
                         _Float16* __restrict__ wbh,   // [NOUT][DIN] fp16 interleaved
                         int* __restrict__ inv, int* __restrict__ meta)
{
  const int b = blockIdx.x;
  const int tid = threadIdx.x;

  if (b == 0) {  // ---- token sort into 128-aligned adapter groups ----
    __shared__ int cnt[4], cur[4];
    if (tid < 4) cnt[tid] = 0;
    __syncthreads();
    for (int t = tid; t < T_TOK; t += 256) atomicAdd(&cnt[indices[t]], 1);
    __syncthreads();
    if (tid == 0) {
      int off = 0;
      for (int a = 0; a < 4; ++a) {
        meta[a] = off;
        meta[5 + a] = off + cnt[a];
        cur[a] = off;
        off = (off + cnt[a] + 127) & ~127;
      }
      meta[4] = off;
    }
    __syncthreads();
    for (int i = tid; i < ROWS_PAD; i += 256) inv[i] = -1;
    __syncthreads();
    for (int t = tid; t < T_TOK; t += 256) {
      int a = indices[t];
      int p = atomicAdd(&cur[a], 1);
      inv[p] = t;
    }
    return;
  }

  if (b <= 1 + T_TOK) {  // ---- x -> fp16, natural order, interleaved ----
    const int row = b - 1;          // 0..T_TOK (T_TOK = zero row)
    const int d0 = tid * 8;
    f16x8 h;
    if (row < T_TOK) {
      const float* src = x + (size_t)row * DIN + d0;
      h = cvt_interleave(*(const float4*)src, *(const float4*)(src + 4));
    } else {
#pragma unroll
      for (int j = 0; j < 8; ++j) h[j] = (_Float16)0.0f;
    }
    *(f16x8*)(xh + (size_t)row * DIN + d0) = h;
    return;
  }

  // ---- Wb row n -> fp16 interleaved ----
  const int n = b - (2 + T_TOK);    // 0..NOUT-1
  const int d0 = tid * 8;
  const float* src = wb + (size_t)n * DIN + d0;
  f16x8 h = cvt_interleave(*(const float4*)src, *(const float4*)(src + 4));
  *(f16x8*)(wbh + (size_t)n * DIN + d0) = h;
}

// ================= kernel 2: GEMM, A via LDS (swizzled DMA), B dequant->registers =================
// 128x128 tile, BK=32, 4 waves (2x2 of 64x64), 16x16x32 f16 MFMA.
// B-fragment for lane (l16,quad), frag nt = qweight word [row n][k0/8+quad] dequanted
// + wbh[row][k0+quad*8 .. +8) — matches MFMA B layout B[n=l16][k=quad*8+j] with the
// global k-interleave [0,4,1,5,2,6,3,7] applied consistently to xh and wbh.
__global__ __launch_bounds__(256) void kreg(
    const _Float16* __restrict__ xh, const _Float16* __restrict__ wbh,
    const int* __restrict__ qw0, const int* __restrict__ qw1,
    const int* __restrict__ qz0, const int* __restrict__ qz1,
    const float* __restrict__ sc0, const float* __restrict__ sc1,
    const float* __restrict__ bias,
    const int* __restrict__ inv, const int* __restrict__ meta,
    float* __restrict__ out)
{
  const int m0 = blockIdx.y * BM;
  if (m0 >= meta[4]) return;
  int ad = 0;                        // adapter uniform per 128-aligned m-tile
  if (m0 >= meta[1]) ad = 1;
  if (m0 >= meta[2]) ad = 2;
  if (m0 >= meta[3]) ad = 3;
  if (m0 >= meta[5 + ad]) return;    // tile entirely pad

  const int n0 = blockIdx.x * BN;
  const int sl = n0 >> 12;           // slice (BN=128 divides OSL=4096)
  const int tid  = threadIdx.x;
  const int wave = tid >> 6;
  const int lane = tid & 63;
  const int quad = lane >> 4;
  const int l16  = lane & 15;
  const int wm = (wave & 1) << 6;
  const int wn = (wave >> 1) << 6;

  __shared__ __align__(16) char smem[8192];   // A tile only: [128][32] f16

  f32x4 acc[4][4];
#pragma unroll
  for (int i = 0; i < 4; ++i)
#pragma unroll
    for (int j = 0; j < 4; ++j) acc[i][j] = (f32x4)0.0f;

  // ---- A staging via global_load_lds, inv-gathered, XOR chunk swizzle ----
  const int kch = (((tid & 3) ^ ((tid >> 3) & 3)) << 3);
  const int rloc = tid >> 2;
  int r0 = inv[m0 + rloc];       if (r0 < 0) r0 = T_TOK;   // pad -> zero row
  int r1 = inv[m0 + rloc + 64];  if (r1 < 0) r1 = T_TOK;
  const _Float16* ag0 = xh + (size_t)r0 * DIN + kch;
  const _Float16* ag1 = xh + (size_t)r1 * DIN + kch;
  char* sa0 = smem +        wave * 1024;
  char* sa1 = smem + 4096 + wave * 1024;
  const int qoff = ((quad ^ ((l16 >> 1) & 3)) << 4);

  // ---- B per-fragment setup: 4 n-frags, row = n0+wn+nt*16+l16 ----
  const int* qwb = sl ? qw1 : qw0;
  const int* qzb = sl ? qz1 : qz0;
  const float* scb = sl ? sc1 : sc0;
  const int qz_base = ad * (OSL / 8);
  const size_t sc_base = (size_t)ad * OSL;

  const int* qp[4];
  const _Float16* wp[4];
  f16x2 s2[4], k2[4];
#pragma unroll
  for (int nt = 0; nt < 4; ++nt) {
    const int row = n0 + wn + nt * 16 + l16;    // absolute out column
    const int o_sl = row & (OSL - 1);
    qp[nt] = qwb + ((size_t)ad * OSL + o_sl) * (DIN / 8) + quad;
    wp[nt] = wbh + (size_t)row * DIN + quad * 8;
    const float s = scb[sc_base + o_sl];
    const int zw = qzb[qz_base + (o_sl >> 3)];
    const int z = (zw >> ((o_sl & 7) << 2)) & 0xF;
    s2[nt][0] = s2[nt][1] = (_Float16)s;
    k2[nt][0] = k2[nt][1] = (_Float16)(float)(-(1024 + z));  // exact int in fp16
  }

  for (int k0 = 0; k0 < DIN; k0 += BK) {
    gload16(ag0, sa0);
    gload16(ag1, sa1);

    // B fragments: dequant + base-add straight into registers
    f16x8 bfr[4];
#pragma unroll
    for (int nt = 0; nt < 4; ++nt) {
      const uint32_t wv = (uint32_t)qp[nt][0];
      union { f16x8 v; f16x2 p[4]; } wb8;
      wb8.v = *(const f16x8*)wp[nt];
      union { f16x8 v; f16x2 p[4]; } h;
#pragma unroll
      for (int j = 0; j < 4; ++j) {
        uint32_t t = ((wv >> (4 * j)) & 0x000F000Fu) | 0x64006400u;
        h.p[j] = (u2h(t) + k2[nt]) * s2[nt] + wb8.p[j];
      }
      bfr[nt] = h.v;
    }

    __syncthreads();
    f16x8 af[4];
#pragma unroll
    for (int t = 0; t < 4; ++t)
      af[t] = *(const f16x8*)(smem + (wm + t * 16 + l16) * 64 + qoff);
#pragma unroll
    for (int mt = 0; mt < 4; ++mt)
#pragma unroll
      for (int nt = 0; nt < 4; ++nt)
        acc[mt][nt] = __builtin_amdgcn_mfma_f32_16x16x32_f16(af[mt], bfr[nt], acc[mt][nt], 0, 0, 0);
    __syncthreads();

    ag0 += BK; ag1 += BK;
#pragma unroll
    for (int nt = 0; nt < 4; ++nt) { qp[nt] += 4; wp[nt] += BK; }
  }

  // epilogue: C/D col=lane&15, row=quad*4+reg; scatter to out[token], +bias
#pragma unroll
  for (int mt = 0; mt < 4; ++mt) {
    const int rowb = m0 + wm + mt * 16 + quad * 4;
    int tk[4];
#pragma unroll
    for (int r = 0; r < 4; ++r) tk[r] = inv[rowb + r];
#pragma unroll
    for (int nt = 0; nt < 4; ++nt) {
      const int col = n0 + wn + nt * 16 + l16;
      const float bv = bias[col];
#pragma unroll
      for (int r = 0; r < 4; ++r) {
        if (tk[r] >= 0)
          out[(size_t)tk[r] * NOUT + col] = acc[mt][nt][r] + bv;
      }
    }
  }
}

extern "C" void kernel_launch(void* const* d_in, const int* in_sizes, int n_in,
                              void* d_out, int out_size, void* d_ws, size_t ws_size,
                              hipStream_t stream) {
  const float* x    = (const float*)d_in[0];
  const float* wb   = (const float*)d_in[1];
  const float* bias = (const float*)d_in[2];
  const int*   qw0  = (const int*)d_in[3];
  const int*   qw1  = (const int*)d_in[4];
  const int*   qz0  = (const int*)d_in[5];
  const int*   qz1  = (const int*)d_in[6];
  const float* sc0  = (const float*)d_in[7];
  const float* sc1  = (const float*)d_in[8];
  const int*   indices = (const int*)d_in[11];
  float* out = (float*)d_out;

  // workspace: xh [(T_TOK+1)*DIN f16] | inv | meta | wbh [NOUT*DIN f16]  (~37 MB)
  char* w = (char*)d_ws;
  _Float16* xh = (_Float16*)w;
  size_t off = (size_t)(T_TOK + 1) * DIN * 2;
  int* inv  = (int*)(w + off);
  int* meta = inv + ROWS_PAD;
  size_t woff = (off + (size_t)ROWS_PAD * 4 + 64 + 255) & ~(size_t)255;
  _Float16* wbh = (_Float16*)(w + woff);

  const int nprep = 2 + T_TOK + NOUT;   // sort + x rows (+zero) + Wb rows
  prep_all<<<nprep, 256, 0, stream>>>(x, wb, indices, xh, wbh, inv, meta);

  dim3 g(NOUT / BN, ROWS_PAD / BM, 1);  // 64 x 11
  kreg<<<g, 256, 0, stream>>>(xh, wbh, qw0, qw1, qz0, qz1, sc0, sc1,
                              bias, inv, meta, out);
}

// Round 5
// 237.313 us; speedup vs baseline: 1.5262x; 1.5262x over previous
//
#include <hip/hip_runtime.h>
#include <hip/hip_bf16.h>
#include <stdint.h>

// Problem constants
#define T_TOK 1024
#define DIN   2048
#define NOUT  8192   // 2*O
#define OSL   4096   // O per slice
#define ROWS_PAD 1408
#define BM 128
#define BN 128
#define BK 32
#define NITER (DIN / BK)   // 64

typedef _Float16 f16x8 __attribute__((ext_vector_type(8)));
typedef _Float16 f16x2 __attribute__((ext_vector_type(2)));
typedef float    f32x4 __attribute__((ext_vector_type(4)));

__device__ __forceinline__ f16x2 u2h(uint32_t u) {
  union { uint32_t u; f16x2 h; } c; c.u = u; return c.h;
}

__device__ __forceinline__ f16x8 cvt_interleave(float4 f0, float4 f1) {
  // k-order [0,4,1,5,2,6,3,7] so packed-nibble pairs (n_j, n_{j+4}) line up
  f16x8 h;
  h[0] = (_Float16)f0.x; h[1] = (_Float16)f1.x;
  h[2] = (_Float16)f0.y; h[3] = (_Float16)f1.y;
  h[4] = (_Float16)f0.z; h[5] = (_Float16)f1.z;
  h[6] = (_Float16)f0.w; h[7] = (_Float16)f1.w;
  return h;
}

// dequant one packed word (8 nibbles -> 4 f16 pairs) and add base weights
__device__ __forceinline__ f16x8 dq_add(uint32_t w, f16x2 s2, f16x2 k2, f16x8 base) {
  union { f16x8 v; f16x2 p[4]; } b, h;
  b.v = base;
#pragma unroll
  for (int j = 0; j < 4; ++j) {
    uint32_t t = ((w >> (4 * j)) & 0x000F000Fu) | 0x64006400u;
    h.p[j] = (u2h(t) + k2) * s2 + b.p[j];   // exact (1024+n)-(1024+z)=n-z, then fma
  }
  return h.v;
}

// ================= kernel 1: sort + x->fp16 + Wb->fp16, one launch =================
__global__ void prep_all(const float* __restrict__ x, const float* __restrict__ wb,
                         const int* __restrict__ indices,
                         _Float16* __restrict__ xh,    // [T_TOK+1][DIN], row T_TOK = zeros
                         _Float16* __restrict__ wbh,   // [NOUT][DIN] fp16 interleaved
                         int* __restrict__ inv, int* __restrict__ meta)
{
  const int b = blockIdx.x;
  const int tid = threadIdx.x;

  if (b == 0) {  // ---- token sort into 128-aligned adapter groups ----
    __shared__ int cnt[4], cur[4];
    if (tid < 4) cnt[tid] = 0;
    __syncthreads();
    for (int t = tid; t < T_TOK; t += 256) atomicAdd(&cnt[indices[t]], 1);
    __syncthreads();
    if (tid == 0) {
      int off = 0;
      for (int a = 0; a < 4; ++a) {
        meta[a] = off;
        meta[5 + a] = off + cnt[a];
        cur[a] = off;
        off = (off + cnt[a] + 127) & ~127;
      }
      meta[4] = off;
    }
    __syncthreads();
    for (int i = tid; i < ROWS_PAD; i += 256) inv[i] = -1;
    __syncthreads();
    for (int t = tid; t < T_TOK; t += 256) {
      int a = indices[t];
      int p = atomicAdd(&cur[a], 1);
      inv[p] = t;
    }
    return;
  }

  if (b <= 1 + T_TOK) {  // ---- x -> fp16, natural order, interleaved ----
    const int row = b - 1;          // 0..T_TOK (T_TOK = zero row)
    const int d0 = tid * 8;
    f16x8 h;
    if (row < T_TOK) {
      const float* src = x + (size_t)row * DIN + d0;
      h = cvt_interleave(*(const float4*)src, *(const float4*)(src + 4));
    } else {
#pragma unroll
      for (int j = 0; j < 8; ++j) h[j] = (_Float16)0.0f;
    }
    *(f16x8*)(xh + (size_t)row * DIN + d0) = h;
    return;
  }

  // ---- Wb row n -> fp16 interleaved ----
  const int n = b - (2 + T_TOK);    // 0..NOUT-1
  const int d0 = tid * 8;
  const float* src = wb + (size_t)n * DIN + d0;
  f16x8 h = cvt_interleave(*(const float4*)src, *(const float4*)(src + 4));
  *(f16x8*)(wbh + (size_t)n * DIN + d0) = h;
}

// ================= kernel 2: pipelined GEMM, all staging via registers =================
// Double-buffered LDS (A+B 16 KB per stage), 1 barrier/iter. Loads for iter k+1
// issue before MFMA(k); NO global_load_lds anywhere so the barrier never forces
// vmcnt(0) -> register prefetch stays in flight across it (the R4 failure mode).
__global__ __launch_bounds__(256) void kpipe(
    const _Float16* __restrict__ xh, const _Float16* __restrict__ wbh,
    const int* __restrict__ qw0, const int* __restrict__ qw1,
    const int* __restrict__ qz0, const int* __restrict__ qz1,
    const float* __restrict__ sc0, const float* __restrict__ sc1,
    const float* __restrict__ bias,
    const int* __restrict__ inv, const int* __restrict__ meta,
    float* __restrict__ out)
{
  const int m0 = blockIdx.y * BM;
  if (m0 >= meta[4]) return;
  int ad = 0;                        // adapter uniform per 128-aligned m-tile
  if (m0 >= meta[1]) ad = 1;
  if (m0 >= meta[2]) ad = 2;
  if (m0 >= meta[3]) ad = 3;
  if (m0 >= meta[5 + ad]) return;    // tile entirely pad

  const int n0 = blockIdx.x * BN;
  const int sl = n0 >> 12;
  const int tid  = threadIdx.x;
  const int wave = tid >> 6;
  const int lane = tid & 63;
  const int quad = lane >> 4;
  const int l16  = lane & 15;
  const int wm = (wave & 1) << 6;
  const int wn = (wave >> 1) << 6;

  // [A0 8K][B0 8K][A1 8K][B1 8K]
  __shared__ __align__(16) char smem[32768];

  f32x4 acc[4][4];
#pragma unroll
  for (int i = 0; i < 4; ++i)
#pragma unroll
    for (int j = 0; j < 4; ++j) acc[i][j] = (f32x4)0.0f;

  // ---- producer roles: thread t stages row srow (A and B), 32-byte half ----
  const int srow = tid >> 1;         // 0..127
  const int half = tid & 1;
  const int swz  = (srow >> 1) & 3;  // XOR chunk swizzle (same law as fragment reads)

  int tok = inv[m0 + srow]; if (tok < 0) tok = T_TOK;       // pad -> zero row
  const _Float16* ap = xh + (size_t)tok * DIN + (half << 4);

  const int o = n0 + srow;
  const int o_sl = o & (OSL - 1);
  const int* qwb = sl ? qw1 : qw0;
  const int* qp = qwb + ((size_t)ad * OSL + o_sl) * (DIN / 8) + (half << 1);
  const _Float16* wp = wbh + (size_t)o * DIN + (half << 4);

  const float s = (sl ? sc1 : sc0)[(size_t)ad * OSL + o_sl];
  const int zw = (sl ? qz1 : qz0)[ad * (OSL / 8) + (o_sl >> 3)];
  const int z = (zw >> ((o_sl & 7) << 2)) & 0xF;
  f16x2 s2; s2[0] = s2[1] = (_Float16)s;
  f16x2 k2; k2[0] = k2[1] = (_Float16)(float)(-(1024 + z));

  // LDS write offsets: stored position p holds source chunk p^swz
  const int c0 = ((half << 1)     ^ swz) << 4;
  const int c1 = (((half << 1) | 1) ^ swz) << 4;
  const int aoff0 = srow * 64 + c0, aoff1 = srow * 64 + c1;
  const int boff0 = 8192 + srow * 64 + c0, boff1 = 8192 + srow * 64 + c1;

  const int qoff = ((quad ^ ((l16 >> 1) & 3)) << 4);

  char* cur = smem;
  char* nxt = smem + 16384;

  // ---- prologue: load + stage k=0 ----
  f16x8 va0 = *(const f16x8*)ap;
  f16x8 va1 = *(const f16x8*)(ap + 8);
  f16x8 vb0 = *(const f16x8*)wp;
  f16x8 vb1 = *(const f16x8*)(wp + 8);
  int2  vq  = *(const int2*)qp;
  ap += BK; wp += BK; qp += 4;

  *(f16x8*)(cur + aoff0) = va0;
  *(f16x8*)(cur + aoff1) = va1;
  *(f16x8*)(cur + boff0) = dq_add((uint32_t)vq.x, s2, k2, vb0);
  *(f16x8*)(cur + boff1) = dq_add((uint32_t)vq.y, s2, k2, vb1);
  __syncthreads();

#pragma unroll 1
  for (int k = 0; k < NITER - 1; ++k) {
    // issue loads for k+1 (consumed after MFMA -> latency covered)
    va0 = *(const f16x8*)ap;
    va1 = *(const f16x8*)(ap + 8);
    vb0 = *(const f16x8*)wp;
    vb1 = *(const f16x8*)(wp + 8);
    vq  = *(const int2*)qp;
    ap += BK; wp += BK; qp += 4;

    f16x8 af[4], bf[4];
#pragma unroll
    for (int t = 0; t < 4; ++t)
      af[t] = *(const f16x8*)(cur + (wm + t * 16 + l16) * 64 + qoff);
#pragma unroll
    for (int t = 0; t < 4; ++t)
      bf[t] = *(const f16x8*)(cur + 8192 + (wn + t * 16 + l16) * 64 + qoff);
#pragma unroll
    for (int mt = 0; mt < 4; ++mt)
#pragma unroll
      for (int nt = 0; nt < 4; ++nt)
        acc[mt][nt] = __builtin_amdgcn_mfma_f32_16x16x32_f16(af[mt], bf[nt], acc[mt][nt], 0, 0, 0);

    // stage k+1 into the other buffer (readers of `cur` unaffected)
    *(f16x8*)(nxt + aoff0) = va0;
    *(f16x8*)(nxt + aoff1) = va1;
    *(f16x8*)(nxt + boff0) = dq_add((uint32_t)vq.x, s2, k2, vb0);
    *(f16x8*)(nxt + boff1) = dq_add((uint32_t)vq.y, s2, k2, vb1);
    __syncthreads();

    char* t = cur; cur = nxt; nxt = t;
  }

  // ---- final iteration (no prefetch) ----
  {
    f16x8 af[4], bf[4];
#pragma unroll
    for (int t = 0; t < 4; ++t)
      af[t] = *(const f16x8*)(cur + (wm + t * 16 + l16) * 64 + qoff);
#pragma unroll
    for (int t = 0; t < 4; ++t)
      bf[t] = *(const f16x8*)(cur + 8192 + (wn + t * 16 + l16) * 64 + qoff);
#pragma unroll
    for (int mt = 0; mt < 4; ++mt)
#pragma unroll
      for (int nt = 0; nt < 4; ++nt)
        acc[mt][nt] = __builtin_amdgcn_mfma_f32_16x16x32_f16(af[mt], bf[nt], acc[mt][nt], 0, 0, 0);
  }

  // ---- epilogue: C/D col=lane&15, row=quad*4+reg; scatter to out[token], +bias ----
#pragma unroll
  for (int mt = 0; mt < 4; ++mt) {
    const int rowb = m0 + wm + mt * 16 + quad * 4;
    int tk[4];
#pragma unroll
    for (int r = 0; r < 4; ++r) tk[r] = inv[rowb + r];
#pragma unroll
    for (int nt = 0; nt < 4; ++nt) {
      const int col = n0 + wn + nt * 16 + l16;
      const float bv = bias[col];
#pragma unroll
      for (int r = 0; r < 4; ++r) {
        if (tk[r] >= 0)
          out[(size_t)tk[r] * NOUT + col] = acc[mt][nt][r] + bv;
      }
    }
  }
}

extern "C" void kernel_launch(void* const* d_in, const int* in_sizes, int n_in,
                              void* d_out, int out_size, void* d_ws, size_t ws_size,
                              hipStream_t stream) {
  const float* x    = (const float*)d_in[0];
  const float* wb   = (const float*)d_in[1];
  const float* bias = (const float*)d_in[2];
  const int*   qw0  = (const int*)d_in[3];
  const int*   qw1  = (const int*)d_in[4];
  const int*   qz0  = (const int*)d_in[5];
  const int*   qz1  = (const int*)d_in[6];
  const float* sc0  = (const float*)d_in[7];
  const float* sc1  = (const float*)d_in[8];
  const int*   indices = (const int*)d_in[11];
  float* out = (float*)d_out;

  // workspace: xh [(T_TOK+1)*DIN f16] | inv | meta | wbh [NOUT*DIN f16]  (~37 MB)
  char* w = (char*)d_ws;
  _Float16* xh = (_Float16*)w;
  size_t off = (size_t)(T_TOK + 1) * DIN * 2;
  int* inv  = (int*)(w + off);
  int* meta = inv + ROWS_PAD;
  size_t woff = (off + (size_t)ROWS_PAD * 4 + 64 + 255) & ~(size_t)255;
  _Float16* wbh = (_Float16*)(w + woff);

  const int nprep = 2 + T_TOK + NOUT;   // sort + x rows (+zero) + Wb rows
  prep_all<<<nprep, 256, 0, stream>>>(x, wb, indices, xh, wbh, inv, meta);

  dim3 g(NOUT / BN, ROWS_PAD / BM, 1);  // 64 x 11
  kpipe<<<g, 256, 0, stream>>>(xh, wbh, qw0, qw1, qz0, qz1, sc0, sc1,
                               bias, inv, meta, out);
}